// Round 16
// baseline (41.328 us; speedup 1.0000x reference)
//
#include <hip/hip_runtime.h>
#include <hip/hip_bf16.h>

typedef float  f32x4  __attribute__((ext_vector_type(4)));
typedef short  s16x8  __attribute__((ext_vector_type(8)));
typedef short  s16x4  __attribute__((ext_vector_type(4)));

#define PIN_LOADS() asm volatile("" ::: "memory")

__device__ __forceinline__ unsigned short f2bf(float f) {
    unsigned int u = __float_as_uint(f);
    unsigned int rnd = 0x7fffu + ((u >> 16) & 1u);   // round-to-nearest-even
    return (unsigned short)((u + rnd) >> 16);
}

// acc(f32x4) += s * unpack_bf16x4(v)
__device__ __forceinline__ void bf4_fma(const s16x4 v, float s, f32x4& a) {
    const uint2 u = *(const uint2*)&v;
    a[0] += s * __uint_as_float(u.x << 16);
    a[1] += s * __uint_as_float(u.x & 0xffff0000u);
    a[2] += s * __uint_as_float(u.y << 16);
    a[3] += s * __uint_as_float(u.y & 0xffff0000u);
}

// K1 prep, three independent block ranges:
//  [0,8)    : Wq f32 -> bf16 B-fragments (frag-linear Wqb)
//  [8,42)   : T2[r] = table_row @ Wq^T (bf16 row-major; B-frags inline from Wq)
//  [42,298) : desc[row] = {qq, s0..s7, diffRow, areaRow, a}  (48 B)
__global__ __launch_bounds__(256)
void h2kt_prep(const float* __restrict__ Wq,
               const float* __restrict__ skill, const float* __restrict__ diff,
               const float* __restrict__ area,
               const int* __restrict__ q, const int* __restrict__ next_q,
               const int* __restrict__ a_arr,
               const int* __restrict__ q2s, const int* __restrict__ q2d,
               const int* __restrict__ q2a,
               unsigned short* __restrict__ Wqb,
               unsigned short* __restrict__ T2,
               int* __restrict__ desc,
               int pad_idx)
{
    const int bid = blockIdx.x, tid = threadIdx.x;

    if (bid < 8) {
        const int s  = bid * 256 + tid;              // 0..2047
        const int f  = s >> 6, sl = s & 63;
        const int jt = f >> 2, kt = f & 3;
        const int row = jt * 16 + (sl & 15);
        const int col = kt * 32 + (sl >> 4) * 8;
        const float4 w0 = *(const float4*)(Wq + row * 128 + col);
        const float4 w1 = *(const float4*)(Wq + row * 128 + col + 4);
        s16x8 v;
        v[0] = (short)f2bf(w0.x); v[1] = (short)f2bf(w0.y);
        v[2] = (short)f2bf(w0.z); v[3] = (short)f2bf(w0.w);
        v[4] = (short)f2bf(w1.x); v[5] = (short)f2bf(w1.y);
        v[6] = (short)f2bf(w1.z); v[7] = (short)f2bf(w1.w);
        *(s16x8*)(Wqb + (size_t)s * 8) = v;
    } else if (bid < 42) {
        const int lane = tid & 63;
        const int cl = lane & 15, grp = lane >> 4;
        const int row16 = ((bid - 8) * 4 + (tid >> 6)) * 16;   // 0..2160
        if (row16 > 2150) return;

        int srow = row16 + cl;
        if (srow > 2150) srow = 2150;
        const float* src = (srow < 2001) ? skill + (size_t)srow * 128
                         : (srow < 2101) ? diff + (size_t)(srow - 2001) * 128
                                         : area + (size_t)(srow - 2101) * 128;
        s16x8 afr[4];
        #pragma unroll
        for (int kt = 0; kt < 4; ++kt) {
            const float4 v0 = *(const float4*)(src + kt * 32 + grp * 8);
            const float4 v1 = *(const float4*)(src + kt * 32 + grp * 8 + 4);
            s16x8 v;
            v[0] = (short)f2bf(v0.x); v[1] = (short)f2bf(v0.y);
            v[2] = (short)f2bf(v0.z); v[3] = (short)f2bf(v0.w);
            v[4] = (short)f2bf(v1.x); v[5] = (short)f2bf(v1.y);
            v[6] = (short)f2bf(v1.z); v[7] = (short)f2bf(v1.w);
            afr[kt] = v;
        }
        #pragma unroll
        for (int jt = 0; jt < 8; ++jt) {
            f32x4 acc = {0.f, 0.f, 0.f, 0.f};
            #pragma unroll
            for (int kt = 0; kt < 4; ++kt) {
                const float* wp = Wq + (jt * 16 + cl) * 128 + kt * 32 + grp * 8;
                const float4 w0 = *(const float4*)(wp);
                const float4 w1 = *(const float4*)(wp + 4);
                s16x8 bf;
                bf[0] = (short)f2bf(w0.x); bf[1] = (short)f2bf(w0.y);
                bf[2] = (short)f2bf(w0.z); bf[3] = (short)f2bf(w0.w);
                bf[4] = (short)f2bf(w1.x); bf[5] = (short)f2bf(w1.y);
                bf[6] = (short)f2bf(w1.z); bf[7] = (short)f2bf(w1.w);
                acc = __builtin_amdgcn_mfma_f32_16x16x32_bf16(afr[kt], bf, acc, 0, 0, 0);
            }
            #pragma unroll
            for (int r = 0; r < 4; ++r) {
                const int orow = row16 + grp * 4 + r;
                if (orow < 2151) T2[(size_t)orow * 128 + jt * 16 + cl] = f2bf(acc[r]);
            }
        }
    } else {
        const int g = (bid - 42) * 256 + tid;        // 0..65535
        const int p = g & 32767;
        const bool isnq = (g >= 32768);
        const int qq = isnq ? next_q[p] : q[p];
        const int4 s03 = *(const int4*)(q2s + (size_t)qq * 8);
        const int4 s47 = *(const int4*)(q2s + (size_t)qq * 8 + 4);
        const int di = q2d[qq];
        const int ai = q2a[qq];
        const int av = isnq ? 1 : a_arr[p];
        int4* d = (int4*)(desc + (size_t)g * 12);
        d[0] = make_int4(qq, s03.x, s03.y, s03.z);
        d[1] = make_int4(s03.w, s47.x, s47.y, s47.z);
        d[2] = make_int4(s47.w, 2001 + di, 2101 + ai, av);
    }
}

// Fused main: ULTRA-THIN waves. 8 waves per 16-row tile (512-thread block).
// Wave w owns rows {w*2, w*2+1}: lane (r=lane>>5, c=lane&31) covers row
// w*2+r, cols 4c..4c+3. Per wave: 3 desc loads, 1 qe load, 10x 8-byte T2
// loads (t[10] = 20 VGPRs -- held ACROSS the MFMA, combine runs after it so
// T2 latency is fully buried), 1 jt of MFMA, 2-3 epilogue stores.
// Phase-peak live regs ~55 < 64 => launch_bounds(512,8) hits the <=64 VGPR
// tier: 32 waves/CU, double R15's 16 (m69: wave count halves at 64/128/256).
__global__ __launch_bounds__(512, 8)
void h2kt_fused(const int* __restrict__ desc,
                const float* __restrict__ ques_table,
                const unsigned short* __restrict__ T2,
                const unsigned short* __restrict__ Wqb,
                const float* __restrict__ bq,
                float* __restrict__ out,
                int pad_idx)
{
    // Q (bf16 16x136) and D (f32 16x132) live in disjoint phases -> union.
    __shared__ __align__(16) unsigned char U[16 * 132 * 4];   // 8448 B
    unsigned short* Q = (unsigned short*)U;    // stride 136 shorts
    float*          D = (float*)U;             // stride 132 floats

    const int tid  = threadIdx.x;
    const int w    = tid >> 6;                 // 0..7
    const int lane = tid & 63;
    const int cl   = lane & 15;
    const int grp  = lane >> 4;
    const int r    = lane >> 5;                // 0/1
    const int c    = lane & 31;                // 4-float col chunk
    const int g0   = blockIdx.x * 16;          // global row base, 0..65520
    const int base = g0 & 32767;
    const bool isnq = (g0 >= 32768);
    const float wq_ = isnq ? 0.0625f : 0.25f;
    const float wr_ = isnq ? 0.3125f : 0.25f;

    const int myrow = w * 2 + r;               // this lane's row (0..15)

    // ---- desc for my row (L2-hot; qq comes from it too) ----
    const int4* P = (const int4*)(desc + (size_t)(g0 + myrow) * 12);
    const int4 i0 = P[0], i1 = P[1], i2 = P[2];
    const int qq = i0.x;
    const int av = i2.w;
    const int sa[8] = {i0.y, i0.z, i0.w, i1.x, i1.y, i1.z, i1.w, i2.x};

    // ---- qe row chunk (the only HBM-cold load; 1 per lane) ----
    const f32x4 qv = *(const f32x4*)(ques_table + (size_t)qq * 128 + c * 4);

    // ---- T2 batch: 10x 8-byte loads, CONSUMED AFTER MFMA ----
    s16x4 t[10];
    #pragma unroll
    for (int i = 0; i < 8; ++i)
        t[i] = *(const s16x4*)(T2 + (size_t)sa[i] * 128 + c * 4);
    t[8] = *(const s16x4*)(T2 + (size_t)i2.y * 128 + c * 4);
    t[9] = *(const s16x4*)(T2 + (size_t)i2.z * 128 + c * 4);
    PIN_LOADS();

    // ---- qe -> bf16(wq*qe) -> LDS Q ----
    {
        ushort4 o;
        o.x = f2bf(wq_ * qv[0]); o.y = f2bf(wq_ * qv[1]);
        o.z = f2bf(wq_ * qv[2]); o.w = f2bf(wq_ * qv[3]);
        *(ushort4*)(Q + (size_t)myrow * 136 + c * 4) = o;
    }

    __syncthreads();   // Q ready

    // ---- A-frags from LDS (MFMA lane layout) ----
    s16x8 afr[4];
    #pragma unroll
    for (int kt = 0; kt < 4; ++kt)
        afr[kt] = *(const s16x8*)(Q + (size_t)cl * 136 + kt * 32 + grp * 8);

    __syncthreads();   // Q consumed -> D may overwrite the union

    // ---- MFMA: wave w does jt = w -> D ----
    {
        const int jt = w;
        f32x4 acc = {0.f, 0.f, 0.f, 0.f};
        #pragma unroll
        for (int kt = 0; kt < 4; ++kt) {
            const s16x8 bf = *(const s16x8*)(Wqb + ((size_t)(jt * 4 + kt) * 64 + lane) * 8);
            acc = __builtin_amdgcn_mfma_f32_16x16x32_bf16(afr[kt], bf, acc, 0, 0, 0);
        }
        #pragma unroll
        for (int rr = 0; rr < 4; ++rr)
            D[(size_t)(grp * 4 + rr) * 132 + jt * 16 + cl] = acc[rr];
    }

    // ---- combine (T2 consumed here; latency fully covered) ----
    int cnt = 0;
    #pragma unroll
    for (int i = 0; i < 8; ++i) cnt += (sa[i] != pad_idx);
    const float cs = cnt > 0 ? wr_ / (float)cnt : 0.f;

    f32x4 rA = {0.f, 0.f, 0.f, 0.f};
    #pragma unroll
    for (int i = 0; i < 8; ++i) bf4_fma(t[i], (sa[i] != pad_idx) ? cs : 0.f, rA);
    bf4_fma(t[8], wr_, rA);
    bf4_fma(t[9], wr_, rA);

    __syncthreads();   // D ready

    // ---- epilogue: my row, cols 4c..4c+3 ----
    const f32x4 bq4 = *(const f32x4*)(bq + c * 4);
    const f32x4 d0  = *(const f32x4*)(D + (size_t)myrow * 132 + c * 4);
    const f32x4 v0  = d0 + rA + bq4;
    const f32x4 z   = {0.f, 0.f, 0.f, 0.f};
    const size_t orow = (size_t)(base + myrow);
    if (!isnq) {
        const bool on = (av != 0);
        *(f32x4*)(out + orow * 384 + c * 4)       = on ? v0 : z;
        *(f32x4*)(out + orow * 384 + 128 + c * 4) = on ? z : v0;
    } else {
        *(f32x4*)(out + orow * 384 + 256 + c * 4) = v0;
    }
}

extern "C" void kernel_launch(void* const* d_in, const int* in_sizes, int n_in,
                              void* d_out, int out_size, void* d_ws, size_t ws_size,
                              hipStream_t stream) {
    const int*   q          = (const int*)d_in[0];
    const int*   a          = (const int*)d_in[1];
    const int*   next_q     = (const int*)d_in[2];
    const float* ques_table = (const float*)d_in[3];
    const float* skill_tab  = (const float*)d_in[4];
    const float* diff_tab   = (const float*)d_in[5];
    const float* area_tab   = (const float*)d_in[6];
    const int*   q2s        = (const int*)d_in[7];
    const int*   q2d        = (const int*)d_in[8];
    const int*   q2a        = (const int*)d_in[9];
    const float* Wq         = (const float*)d_in[10];
    const float* bq         = (const float*)d_in[11];
    float* out = (float*)d_out;

    const int NS = in_sizes[4] / 128;       // 2001
    const int pad_idx = NS - 1;             // 2000

    // ws: desc (65536*48B = 3 MiB) | Wqb (32 KiB) | T2 (~550 KiB)
    int*            descp = (int*)d_ws;
    unsigned short* Wqb   = (unsigned short*)((char*)d_ws + (size_t)65536 * 48);
    unsigned short* T2    = Wqb + (size_t)2048 * 8;

    h2kt_prep<<<298, 256, 0, stream>>>(Wq, skill_tab, diff_tab, area_tab,
                                       q, next_q, a, q2s, q2d, q2a,
                                       Wqb, T2, descp, pad_idx);
    h2kt_fused<<<4096, 512, 0, stream>>>(descp, ques_table, T2, Wqb, bq, out, pad_idx);
}

// Round 17
// 39.041 us; speedup vs baseline: 1.0586x; 1.0586x over previous
//
#include <hip/hip_runtime.h>
#include <hip/hip_bf16.h>

typedef float  f32x4  __attribute__((ext_vector_type(4)));
typedef short  s16x8  __attribute__((ext_vector_type(8)));

#define PIN_LOADS() asm volatile("" ::: "memory")

__device__ __forceinline__ unsigned short f2bf(float f) {
    unsigned int u = __float_as_uint(f);
    unsigned int rnd = 0x7fffu + ((u >> 16) & 1u);   // round-to-nearest-even
    return (unsigned short)((u + rnd) >> 16);
}

// acc += s * unpack_bf16x8(v)
__device__ __forceinline__ void bf8_fma(const s16x8 v, float s, f32x4& a0, f32x4& a1) {
    const uint4 u = *(const uint4*)&v;
    a0[0] += s * __uint_as_float(u.x << 16);
    a0[1] += s * __uint_as_float(u.x & 0xffff0000u);
    a0[2] += s * __uint_as_float(u.y << 16);
    a0[3] += s * __uint_as_float(u.y & 0xffff0000u);
    a1[0] += s * __uint_as_float(u.z << 16);
    a1[1] += s * __uint_as_float(u.z & 0xffff0000u);
    a1[2] += s * __uint_as_float(u.w << 16);
    a1[3] += s * __uint_as_float(u.w & 0xffff0000u);
}

// K1 prep, three independent block ranges:
//  [0,8)    : Wq f32 -> bf16 B-fragments (frag-linear Wqb)
//  [8,42)   : T2[r] = table_row @ Wq^T (bf16 row-major; B-frags inline from Wq)
//  [42,298) : desc[row] = {qq, s0..s7, diffRow, areaRow, a}  (48 B)
__global__ __launch_bounds__(256)
void h2kt_prep(const float* __restrict__ Wq,
               const float* __restrict__ skill, const float* __restrict__ diff,
               const float* __restrict__ area,
               const int* __restrict__ q, const int* __restrict__ next_q,
               const int* __restrict__ a_arr,
               const int* __restrict__ q2s, const int* __restrict__ q2d,
               const int* __restrict__ q2a,
               unsigned short* __restrict__ Wqb,
               unsigned short* __restrict__ T2,
               int* __restrict__ desc,
               int pad_idx)
{
    const int bid = blockIdx.x, tid = threadIdx.x;

    if (bid < 8) {
        const int s  = bid * 256 + tid;              // 0..2047
        const int f  = s >> 6, sl = s & 63;
        const int jt = f >> 2, kt = f & 3;
        const int row = jt * 16 + (sl & 15);
        const int col = kt * 32 + (sl >> 4) * 8;
        const float4 w0 = *(const float4*)(Wq + row * 128 + col);
        const float4 w1 = *(const float4*)(Wq + row * 128 + col + 4);
        s16x8 v;
        v[0] = (short)f2bf(w0.x); v[1] = (short)f2bf(w0.y);
        v[2] = (short)f2bf(w0.z); v[3] = (short)f2bf(w0.w);
        v[4] = (short)f2bf(w1.x); v[5] = (short)f2bf(w1.y);
        v[6] = (short)f2bf(w1.z); v[7] = (short)f2bf(w1.w);
        *(s16x8*)(Wqb + (size_t)s * 8) = v;
    } else if (bid < 42) {
        const int lane = tid & 63;
        const int cl = lane & 15, grp = lane >> 4;
        const int row16 = ((bid - 8) * 4 + (tid >> 6)) * 16;   // 0..2160
        if (row16 > 2150) return;

        int srow = row16 + cl;
        if (srow > 2150) srow = 2150;
        const float* src = (srow < 2001) ? skill + (size_t)srow * 128
                         : (srow < 2101) ? diff + (size_t)(srow - 2001) * 128
                                         : area + (size_t)(srow - 2101) * 128;
        s16x8 afr[4];
        #pragma unroll
        for (int kt = 0; kt < 4; ++kt) {
            const float4 v0 = *(const float4*)(src + kt * 32 + grp * 8);
            const float4 v1 = *(const float4*)(src + kt * 32 + grp * 8 + 4);
            s16x8 v;
            v[0] = (short)f2bf(v0.x); v[1] = (short)f2bf(v0.y);
            v[2] = (short)f2bf(v0.z); v[3] = (short)f2bf(v0.w);
            v[4] = (short)f2bf(v1.x); v[5] = (short)f2bf(v1.y);
            v[6] = (short)f2bf(v1.z); v[7] = (short)f2bf(v1.w);
            afr[kt] = v;
        }
        #pragma unroll
        for (int jt = 0; jt < 8; ++jt) {
            f32x4 acc = {0.f, 0.f, 0.f, 0.f};
            #pragma unroll
            for (int kt = 0; kt < 4; ++kt) {
                const float* wp = Wq + (jt * 16 + cl) * 128 + kt * 32 + grp * 8;
                const float4 w0 = *(const float4*)(wp);
                const float4 w1 = *(const float4*)(wp + 4);
                s16x8 bf;
                bf[0] = (short)f2bf(w0.x); bf[1] = (short)f2bf(w0.y);
                bf[2] = (short)f2bf(w0.z); bf[3] = (short)f2bf(w0.w);
                bf[4] = (short)f2bf(w1.x); bf[5] = (short)f2bf(w1.y);
                bf[6] = (short)f2bf(w1.z); bf[7] = (short)f2bf(w1.w);
                acc = __builtin_amdgcn_mfma_f32_16x16x32_bf16(afr[kt], bf, acc, 0, 0, 0);
            }
            #pragma unroll
            for (int r = 0; r < 4; ++r) {
                const int orow = row16 + grp * 4 + r;
                if (orow < 2151) T2[(size_t)orow * 128 + jt * 16 + cl] = f2bf(acc[r]);
            }
        }
    } else {
        const int g = (bid - 42) * 256 + tid;        // 0..65535
        const int p = g & 32767;
        const bool isnq = (g >= 32768);
        const int qq = isnq ? next_q[p] : q[p];
        const int4 s03 = *(const int4*)(q2s + (size_t)qq * 8);
        const int4 s47 = *(const int4*)(q2s + (size_t)qq * 8 + 4);
        const int di = q2d[qq];
        const int ai = q2a[qq];
        const int av = isnq ? 1 : a_arr[p];
        int4* d = (int4*)(desc + (size_t)g * 12);
        d[0] = make_int4(qq, s03.x, s03.y, s03.z);
        d[1] = make_int4(s03.w, s47.x, s47.y, s47.z);
        d[2] = make_int4(s47.w, 2001 + di, 2101 + ai, av);
    }
}

// Fused main: R15 thin-wave optimum (4 waves / 16-row tile) + DEFERRED
// COMBINE: the T2 batch t[10] is held across the MFMA and consumed after it,
// burying T2's L2 latency under Q-store/barrier/A-frag-read/MFMA. Peak live
// regs ~85 (t=40, afr=16, acc+misc ~30) -- below the ~100 spill point seen
// in R12. Everything else identical to R15 (39.8 us).
__global__ __launch_bounds__(256, 4)
void h2kt_fused(const int* __restrict__ desc,
                const float* __restrict__ ques_table,
                const unsigned short* __restrict__ T2,
                const unsigned short* __restrict__ Wqb,
                const float* __restrict__ bq,
                float* __restrict__ out,
                int pad_idx)
{
    // Q (bf16 16x136) and D (f32 16x132) live in disjoint phases -> union.
    __shared__ __align__(16) unsigned char U[16 * 132 * 4];   // 8448 B
    unsigned short* Q = (unsigned short*)U;    // stride 136 shorts
    float*          D = (float*)U;             // stride 132 floats

    const int tid  = threadIdx.x;
    const int w    = tid >> 6;                 // 0..3
    const int lane = tid & 63;
    const int cl   = lane & 15;
    const int grp  = lane >> 4;
    const int r2   = lane >> 5;                // 0/1
    const int c    = lane & 31;                // f32x4 chunk
    const int g0   = blockIdx.x * 16;          // global row base, 0..65520
    const int base = g0 & 32767;
    const bool isnq = (g0 >= 32768);
    const float wq_ = isnq ? 0.0625f : 0.25f;
    const float wr_ = isnq ? 0.3125f : 0.25f;

    const int myrow = w * 4 + grp;             // this lane's combine/epilogue row

    // ---- descriptor loads (L2-hot) ----
    const int qq0 = desc[(size_t)(g0 + w * 4 + 0 + r2) * 12];
    const int qq1 = desc[(size_t)(g0 + w * 4 + 2 + r2) * 12];
    const int4* P = (const int4*)(desc + (size_t)(g0 + myrow) * 12);
    const int4 i0 = P[0], i1 = P[1], i2 = P[2];

    // ---- qe rows for this wave (rows w*4 .. w*4+3), 2 HBM loads/lane ----
    const f32x4 qv0 = *(const f32x4*)(ques_table + (size_t)qq0 * 128 + c * 4);
    const f32x4 qv1 = *(const f32x4*)(ques_table + (size_t)qq1 * 128 + c * 4);

    const int sa[8] = {i0.y, i0.z, i0.w, i1.x, i1.y, i1.z, i1.w, i2.x};
    const int av = i2.w;

    // ---- ONE T2 batch (10 loads; L2-hot) -- consumed AFTER the MFMA ----
    s16x8 t[10];
    #pragma unroll
    for (int i = 0; i < 8; ++i)
        t[i] = *(const s16x8*)(T2 + (size_t)sa[i] * 128 + cl * 8);
    t[8] = *(const s16x8*)(T2 + (size_t)i2.y * 128 + cl * 8);
    t[9] = *(const s16x8*)(T2 + (size_t)i2.z * 128 + cl * 8);
    PIN_LOADS();

    // ---- qe -> bf16(wq*qe) -> LDS Q (this wave's 4 rows) ----
    {
        ushort4 o;
        o.x = f2bf(wq_ * qv0[0]); o.y = f2bf(wq_ * qv0[1]);
        o.z = f2bf(wq_ * qv0[2]); o.w = f2bf(wq_ * qv0[3]);
        *(ushort4*)(Q + (size_t)(w * 4 + 0 + r2) * 136 + c * 4) = o;
        o.x = f2bf(wq_ * qv1[0]); o.y = f2bf(wq_ * qv1[1]);
        o.z = f2bf(wq_ * qv1[2]); o.w = f2bf(wq_ * qv1[3]);
        *(ushort4*)(Q + (size_t)(w * 4 + 2 + r2) * 136 + c * 4) = o;
    }

    __syncthreads();   // Q ready

    // ---- A-frags from LDS ----
    s16x8 afr[4];
    #pragma unroll
    for (int kt = 0; kt < 4; ++kt)
        afr[kt] = *(const s16x8*)(Q + (size_t)cl * 136 + kt * 32 + grp * 8);

    __syncthreads();   // Q consumed -> D may overwrite the union

    // ---- MFMA (wave w does jt = w*2, w*2+1) -> D ----
    #pragma unroll
    for (int jt2 = 0; jt2 < 2; ++jt2) {
        const int jt = w * 2 + jt2;
        f32x4 acc = {0.f, 0.f, 0.f, 0.f};
        #pragma unroll
        for (int kt = 0; kt < 4; ++kt) {
            const s16x8 bf = *(const s16x8*)(Wqb + ((size_t)(jt * 4 + kt) * 64 + lane) * 8);
            acc = __builtin_amdgcn_mfma_f32_16x16x32_bf16(afr[kt], bf, acc, 0, 0, 0);
        }
        #pragma unroll
        for (int r = 0; r < 4; ++r)
            D[(size_t)(grp * 4 + r) * 132 + jt * 16 + cl] = acc[r];
    }

    // ---- DEFERRED combine (T2 latency buried under everything above) ----
    int cnt = 0;
    #pragma unroll
    for (int i = 0; i < 8; ++i) cnt += (sa[i] != pad_idx);
    const float cs = cnt > 0 ? wr_ / (float)cnt : 0.f;

    f32x4 rA = {0,0,0,0}, rB = {0,0,0,0};
    #pragma unroll
    for (int i = 0; i < 8; ++i) bf8_fma(t[i], (sa[i] != pad_idx) ? cs : 0.f, rA, rB);
    bf8_fma(t[8], wr_, rA, rB);
    bf8_fma(t[9], wr_, rA, rB);

    __syncthreads();   // D ready

    // ---- epilogue: this lane's row (matches rA/rB), masked concat ----
    const f32x4 bq0 = *(const f32x4*)(bq + cl * 8);
    const f32x4 bq1 = *(const f32x4*)(bq + cl * 8 + 4);
    const f32x4 z = {0.f, 0.f, 0.f, 0.f};
    {
        const f32x4 d0 = *(const f32x4*)(D + (size_t)myrow * 132 + cl * 8);
        const f32x4 d1 = *(const f32x4*)(D + (size_t)myrow * 132 + cl * 8 + 4);
        const f32x4 v0 = d0 + rA + bq0;
        const f32x4 v1 = d1 + rB + bq1;
        const size_t orow = (size_t)(base + myrow);
        if (!isnq) {
            const bool on = (av != 0);
            *(f32x4*)(out + orow * 384 + cl * 8)           = on ? v0 : z;
            *(f32x4*)(out + orow * 384 + cl * 8 + 4)       = on ? v1 : z;
            *(f32x4*)(out + orow * 384 + 128 + cl * 8)     = on ? z : v0;
            *(f32x4*)(out + orow * 384 + 128 + cl * 8 + 4) = on ? z : v1;
        } else {
            *(f32x4*)(out + orow * 384 + 256 + cl * 8)     = v0;
            *(f32x4*)(out + orow * 384 + 256 + cl * 8 + 4) = v1;
        }
    }
}

extern "C" void kernel_launch(void* const* d_in, const int* in_sizes, int n_in,
                              void* d_out, int out_size, void* d_ws, size_t ws_size,
                              hipStream_t stream) {
    const int*   q          = (const int*)d_in[0];
    const int*   a          = (const int*)d_in[1];
    const int*   next_q     = (const int*)d_in[2];
    const float* ques_table = (const float*)d_in[3];
    const float* skill_tab  = (const float*)d_in[4];
    const float* diff_tab   = (const float*)d_in[5];
    const float* area_tab   = (const float*)d_in[6];
    const int*   q2s        = (const int*)d_in[7];
    const int*   q2d        = (const int*)d_in[8];
    const int*   q2a        = (const int*)d_in[9];
    const float* Wq         = (const float*)d_in[10];
    const float* bq         = (const float*)d_in[11];
    float* out = (float*)d_out;

    const int NS = in_sizes[4] / 128;       // 2001
    const int pad_idx = NS - 1;             // 2000

    // ws: desc (65536*48B = 3 MiB) | Wqb (32 KiB) | T2 (~550 KiB)
    int*            descp = (int*)d_ws;
    unsigned short* Wqb   = (unsigned short*)((char*)d_ws + (size_t)65536 * 48);
    unsigned short* T2    = Wqb + (size_t)2048 * 8;

    h2kt_prep<<<298, 256, 0, stream>>>(Wq, skill_tab, diff_tab, area_tab,
                                       q, next_q, a, q2s, q2d, q2a,
                                       Wqb, T2, descp, pad_idx);
    h2kt_fused<<<4096, 256, 0, stream>>>(descp, ques_table, T2, Wqb, bq, out, pad_idx);
}